// Round 1
// baseline (1254.452 us; speedup 1.0000x reference)
//
#include <hip/hip_runtime.h>

#define NN 100000
#define NE 1600000
#define F 64
#define NG 64
#define BN_EPS 1e-5f

__device__ __forceinline__ float fatomic_add(float* p, float v) {
    return unsafeAtomicAdd(p, v);   // native global_atomic_add_f32 on gfx9xx
}

// deg[i]=1 (self loop), zero pooled + sums
__global__ void k_init(int* __restrict__ deg, float* __restrict__ pooled,
                       float* __restrict__ sums) {
    int i = blockIdx.x * blockDim.x + threadIdx.x;
    if (i < NN) deg[i] = 1;
    if (i < NG * F) pooled[i] = 0.f;
    if (i < 2 * F) sums[i] = 0.f;
}

__global__ void k_deg(const int* __restrict__ dst, int* __restrict__ deg) {
    int e = blockIdx.x * blockDim.x + threadIdx.x;
    if (e < NE) atomicAdd(&deg[dst[e]], 1);
}

__global__ void k_dinv(const int* __restrict__ deg, float* __restrict__ dinv) {
    int i = blockIdx.x * blockDim.x + threadIdx.x;
    if (i < NN) dinv[i] = rsqrtf((float)deg[i]);
}

__global__ void k_norm(const int* __restrict__ src, const int* __restrict__ dst,
                       const float* __restrict__ dinv, float* __restrict__ norm) {
    int e = blockIdx.x * blockDim.x + threadIdx.x;
    if (e < NE) norm[e] = dinv[src[e]] * dinv[dst[e]];
}

// hout[n,f] = dinv[n]^2 * hin[n,f]   (self-loop term, also initializes hout)
__global__ void k_self(const float* __restrict__ hin, const float* __restrict__ dinv,
                       float* __restrict__ hout) {
    int idx = blockIdx.x * blockDim.x + threadIdx.x;   // NN*F
    if (idx >= NN * F) return;
    int n = idx >> 6;
    float d = dinv[n];
    hout[idx] = d * d * hin[idx];
}

// hout[dst,f] += norm[e] * hin[src,f]
__global__ void k_edge(const int* __restrict__ src, const int* __restrict__ dst,
                       const float* __restrict__ norm, const float* __restrict__ hin,
                       float* __restrict__ hout) {
    int idx = blockIdx.x * blockDim.x + threadIdx.x;   // NE*F
    if (idx >= NE * F) return;
    int e = idx >> 6, f = idx & 63;
    int s = src[e], t = dst[e];
    float w = norm[e];
    fatomic_add(&hout[t * F + f], w * hin[s * F + f]);
}

// y = relu(h @ W^T + b); accumulate per-feature sum/sumsq into sums[0:64]/[64:128]
__global__ __launch_bounds__(256) void k_linear(const float* __restrict__ h,
                                                const float* __restrict__ Wg,
                                                const float* __restrict__ bg,
                                                float* __restrict__ y,
                                                float* __restrict__ sums) {
    __shared__ float Wt[64][65];    // Wt[f][j] = W[j][f], padded: conflict-free both ways
    __shared__ float hrow[4][64];
    __shared__ float red[2][4][64];
    int tid = threadIdx.x;
    int j = tid & 63, nl = tid >> 6;
    for (int i = tid; i < 64 * 64; i += 256)
        Wt[i & 63][i >> 6] = Wg[i];
    float bj = bg[j];
    float lsum = 0.f, lsq = 0.f;
    int base = blockIdx.x * 64;
    for (int it = 0; it < 16; ++it) {
        int n0 = base + it * 4;
        __syncthreads();                         // covers Wt (first iter) + hrow reuse
        int nidx = n0 + (tid >> 6);
        hrow[tid >> 6][tid & 63] = (nidx < NN) ? h[(size_t)nidx * 64 + (tid & 63)] : 0.f;
        __syncthreads();
        int n = n0 + nl;
        if (n < NN) {
            float acc = bj;
#pragma unroll
            for (int f = 0; f < 64; ++f)
                acc = fmaf(hrow[nl][f], Wt[f][j], acc);
            acc = fmaxf(acc, 0.f);
            y[(size_t)n * 64 + j] = acc;
            lsum += acc; lsq += acc * acc;
        }
    }
    red[0][nl][j] = lsum;
    red[1][nl][j] = lsq;
    __syncthreads();
    if (nl == 0) {
        float s = red[0][0][j] + red[0][1][j] + red[0][2][j] + red[0][3][j];
        float q = red[1][0][j] + red[1][1][j] + red[1][2][j] + red[1][3][j];
        fatomic_add(&sums[j], s);
        fatomic_add(&sums[64 + j], q);
    }
}

// fold BN into per-feature scale/shift: out = h*a + c
__global__ void k_bnp(const float* __restrict__ sums, const float* __restrict__ gamma,
                      const float* __restrict__ beta, float* __restrict__ ac) {
    int j = threadIdx.x;   // 64
    float mean = sums[j] * (1.0f / NN);
    float var = sums[64 + j] * (1.0f / NN) - mean * mean;
    float rinv = rsqrtf(var + BN_EPS);
    float a = gamma[j] * rinv;
    ac[j] = a;
    ac[64 + j] = beta[j] - mean * a;
}

// outh = y*a + c (in place ok); pooled += segment_sum (batch sorted -> run-length acc)
__global__ __launch_bounds__(256) void k_normpool(const float* __restrict__ y,
                                                  const int* __restrict__ batch,
                                                  const float* __restrict__ ac,
                                                  float* __restrict__ outh,
                                                  float* __restrict__ pooled) {
    int tid = threadIdx.x;
    int j = tid & 63, nl = tid >> 6;
    float a = ac[j], c = ac[64 + j];
    int base = blockIdx.x * 256;
    int curg = -1;
    float acc = 0.f;
    for (int it = 0; it < 64; ++it) {
        int n = base + it * 4 + nl;      // monotone per thread; batch sorted
        if (n >= NN) break;
        int g = batch[n];
        float v = fmaf(y[(size_t)n * 64 + j], a, c);
        outh[(size_t)n * 64 + j] = v;
        if (g != curg) {
            if (curg >= 0) fatomic_add(&pooled[curg * 64 + j], acc);
            curg = g; acc = 0.f;
        }
        acc += v;
    }
    if (curg >= 0) fatomic_add(&pooled[curg * 64 + j], acc);
}

extern "C" void kernel_launch(void* const* d_in, const int* in_sizes, int n_in,
                              void* d_out, int out_size, void* d_ws, size_t ws_size,
                              hipStream_t stream) {
    const float* x     = (const float*)d_in[0];
    const int*   ei    = (const int*)d_in[1];
    const int*   batch = (const int*)d_in[2];
    const float* W     = (const float*)d_in[3];
    const float* b     = (const float*)d_in[4];
    const float* gamma = (const float*)d_in[5];
    const float* beta  = (const float*)d_in[6];
    const int* src = ei;
    const int* dst = ei + NE;

    float* pooled = (float*)d_out;
    float* outh   = (float*)d_out + NG * F;   // doubles as ping-pong buf1

    char* w = (char*)d_ws;
    int*   deg  = (int*)w;    w += sizeof(int) * NN;
    float* dinv = (float*)w;  w += sizeof(float) * NN;
    float* norm = (float*)w;  w += sizeof(float) * NE;
    float* sums = (float*)w;  w += sizeof(float) * 2 * F;
    float* ac   = (float*)w;  w += sizeof(float) * 2 * F;
    float* buf0 = (float*)w;  // NN*F floats

    const int B = 256;
    dim3 blk(B);

    k_init<<<dim3((NN + B - 1) / B), blk, 0, stream>>>(deg, pooled, sums);
    k_deg<<<dim3((NE + B - 1) / B), blk, 0, stream>>>(dst, deg);
    k_dinv<<<dim3((NN + B - 1) / B), blk, 0, stream>>>(deg, dinv);
    k_norm<<<dim3((NE + B - 1) / B), blk, 0, stream>>>(src, dst, dinv, norm);

    dim3 gs((NN * F) / B);        // 25000
    dim3 ge((NE * F) / B);        // 400000

    // hop 1: x -> buf0
    k_self<<<gs, blk, 0, stream>>>(x, dinv, buf0);
    k_edge<<<ge, blk, 0, stream>>>(src, dst, norm, x, buf0);
    // hop 2: buf0 -> outh
    k_self<<<gs, blk, 0, stream>>>(buf0, dinv, outh);
    k_edge<<<ge, blk, 0, stream>>>(src, dst, norm, buf0, outh);
    // hop 3: outh -> buf0
    k_self<<<gs, blk, 0, stream>>>(outh, dinv, buf0);
    k_edge<<<ge, blk, 0, stream>>>(src, dst, norm, outh, buf0);

    // linear + relu + BN stats: buf0 -> outh(y)
    k_linear<<<dim3((NN + 63) / 64), blk, 0, stream>>>(buf0, W, b, outh, sums);
    k_bnp<<<dim3(1), dim3(64), 0, stream>>>(sums, gamma, beta, ac);
    // normalize in place + pool
    k_normpool<<<dim3((NN + 255) / 256), blk, 0, stream>>>(outh, batch, ac, outh, pooled);
}

// Round 2
// 758.826 us; speedup vs baseline: 1.6531x; 1.6531x over previous
//
#include <hip/hip_runtime.h>

#define NN 100000
#define NE 1600000
#define F 64
#define NG 64
#define BN_EPS 1e-5f

__device__ __forceinline__ float fatomic_add(float* p, float v) {
    return unsafeAtomicAdd(p, v);   // native global_atomic_add_f32
}

// deg[i]=1 (self loop), zero pooled + sums
__global__ void k_init(int* __restrict__ deg, float* __restrict__ pooled,
                       float* __restrict__ sums) {
    int i = blockIdx.x * blockDim.x + threadIdx.x;
    if (i < NN) deg[i] = 1;
    if (i < NG * F) pooled[i] = 0.f;
    if (i < 2 * F) sums[i] = 0.f;
}

__global__ void k_deg(const int* __restrict__ dst, int* __restrict__ deg) {
    int e = blockIdx.x * blockDim.x + threadIdx.x;
    if (e < NE) atomicAdd(&deg[dst[e]], 1);
}

__global__ void k_dinv(const int* __restrict__ deg, float* __restrict__ dinv) {
    int i = blockIdx.x * blockDim.x + threadIdx.x;
    if (i < NN) dinv[i] = rsqrtf((float)deg[i]);
}

// Single-block exclusive scan of (deg[i]-1) -> offs; also initializes cur=offs.
__global__ __launch_bounds__(1024) void k_scan(const int* __restrict__ deg,
                                               int* __restrict__ offs,
                                               int* __restrict__ cur) {
    __shared__ int lsum[1024];
    int t = threadIdx.x;
    const int CH = (NN + 1023) / 1024;     // 98
    int beg = t * CH, end = min(beg + CH, NN);
    int s = 0;
    for (int i = beg; i < end; ++i) s += deg[i] - 1;
    lsum[t] = s;
    __syncthreads();
    for (int off = 1; off < 1024; off <<= 1) {
        int v = (t >= off) ? lsum[t - off] : 0;
        __syncthreads();
        lsum[t] += v;
        __syncthreads();
    }
    int run = (t > 0) ? lsum[t - 1] : 0;   // exclusive prefix
    for (int i = beg; i < end; ++i) {
        offs[i] = run; cur[i] = run;
        run += deg[i] - 1;
    }
    if (t == 1023) offs[NN] = lsum[1023];  // == NE
}

// scatter src index into CSR slot of its dst
__global__ void k_scatter(const int* __restrict__ src, const int* __restrict__ dst,
                          int* __restrict__ cur, int* __restrict__ csrc) {
    int e = blockIdx.x * blockDim.x + threadIdx.x;
    if (e >= NE) return;
    int pos = atomicAdd(&cur[dst[e]], 1);
    csrc[pos] = src[e];
}

// hout[n,:] = dinv[n]^2*hin[n,:] + sum_{s in N_in(n)} dinv[s]*dinv[n]*hin[s,:]
// one wave per node; 64 lanes = 64 features
__global__ __launch_bounds__(256) void k_hop(const int* __restrict__ offs,
                                             const int* __restrict__ csrc,
                                             const float* __restrict__ dinv,
                                             const float* __restrict__ hin,
                                             float* __restrict__ hout) {
    int n = blockIdx.x * 4 + (threadIdx.x >> 6);
    if (n >= NN) return;
    int f = threadIdx.x & 63;
    float dn = dinv[n];
    float acc = dn * dn * hin[(size_t)n * F + f];
    int e = offs[n], end = offs[n + 1];
    for (; e + 4 <= end; e += 4) {
        int s0 = csrc[e], s1 = csrc[e + 1], s2 = csrc[e + 2], s3 = csrc[e + 3];
        float w0 = dinv[s0], w1 = dinv[s1], w2 = dinv[s2], w3 = dinv[s3];
        float h0 = hin[(size_t)s0 * F + f];
        float h1 = hin[(size_t)s1 * F + f];
        float h2 = hin[(size_t)s2 * F + f];
        float h3 = hin[(size_t)s3 * F + f];
        acc += dn * (w0 * h0 + w1 * h1 + w2 * h2 + w3 * h3);
    }
    for (; e < end; ++e) {
        int s = csrc[e];
        acc += dn * dinv[s] * hin[(size_t)s * F + f];
    }
    hout[(size_t)n * F + f] = acc;
}

// y = relu(h @ W^T + b); accumulate per-feature sum/sumsq
__global__ __launch_bounds__(256) void k_linear(const float* __restrict__ h,
                                                const float* __restrict__ Wg,
                                                const float* __restrict__ bg,
                                                float* __restrict__ y,
                                                float* __restrict__ sums) {
    __shared__ float Wt[64][65];
    __shared__ float hrow[4][64];
    __shared__ float red[2][4][64];
    int tid = threadIdx.x;
    int j = tid & 63, nl = tid >> 6;
    for (int i = tid; i < 64 * 64; i += 256)
        Wt[i & 63][i >> 6] = Wg[i];
    float bj = bg[j];
    float lsum = 0.f, lsq = 0.f;
    int base = blockIdx.x * 64;
    for (int it = 0; it < 16; ++it) {
        int n0 = base + it * 4;
        __syncthreads();
        int nidx = n0 + nl;
        hrow[nl][j] = (nidx < NN) ? h[(size_t)nidx * 64 + j] : 0.f;
        __syncthreads();
        int n = n0 + nl;
        if (n < NN) {
            float acc = bj;
#pragma unroll
            for (int ff = 0; ff < 64; ++ff)
                acc = fmaf(hrow[nl][ff], Wt[ff][j], acc);
            acc = fmaxf(acc, 0.f);
            y[(size_t)n * 64 + j] = acc;
            lsum += acc; lsq += acc * acc;
        }
    }
    red[0][nl][j] = lsum;
    red[1][nl][j] = lsq;
    __syncthreads();
    if (nl == 0) {
        float s = red[0][0][j] + red[0][1][j] + red[0][2][j] + red[0][3][j];
        float q = red[1][0][j] + red[1][1][j] + red[1][2][j] + red[1][3][j];
        fatomic_add(&sums[j], s);
        fatomic_add(&sums[64 + j], q);
    }
}

__global__ void k_bnp(const float* __restrict__ sums, const float* __restrict__ gamma,
                      const float* __restrict__ beta, float* __restrict__ ac) {
    int j = threadIdx.x;   // 64
    float mean = sums[j] * (1.0f / NN);
    float var = sums[64 + j] * (1.0f / NN) - mean * mean;
    float rinv = rsqrtf(var + BN_EPS);
    float a = gamma[j] * rinv;
    ac[j] = a;
    ac[64 + j] = beta[j] - mean * a;
}

__global__ __launch_bounds__(256) void k_normpool(const float* __restrict__ y,
                                                  const int* __restrict__ batch,
                                                  const float* __restrict__ ac,
                                                  float* __restrict__ outh,
                                                  float* __restrict__ pooled) {
    int tid = threadIdx.x;
    int j = tid & 63, nl = tid >> 6;
    float a = ac[j], c = ac[64 + j];
    int base = blockIdx.x * 256;
    int curg = -1;
    float acc = 0.f;
    for (int it = 0; it < 64; ++it) {
        int n = base + it * 4 + nl;
        if (n >= NN) break;
        int g = batch[n];
        float v = fmaf(y[(size_t)n * 64 + j], a, c);
        outh[(size_t)n * 64 + j] = v;
        if (g != curg) {
            if (curg >= 0) fatomic_add(&pooled[curg * 64 + j], acc);
            curg = g; acc = 0.f;
        }
        acc += v;
    }
    if (curg >= 0) fatomic_add(&pooled[curg * 64 + j], acc);
}

extern "C" void kernel_launch(void* const* d_in, const int* in_sizes, int n_in,
                              void* d_out, int out_size, void* d_ws, size_t ws_size,
                              hipStream_t stream) {
    const float* x     = (const float*)d_in[0];
    const int*   ei    = (const int*)d_in[1];
    const int*   batch = (const int*)d_in[2];
    const float* W     = (const float*)d_in[3];
    const float* b     = (const float*)d_in[4];
    const float* gamma = (const float*)d_in[5];
    const float* beta  = (const float*)d_in[6];
    const int* src = ei;
    const int* dst = ei + NE;

    float* pooled = (float*)d_out;
    float* outh   = (float*)d_out + NG * F;   // also ping-pong buffer

    char* w = (char*)d_ws;
    float* dinv = (float*)w;  w += sizeof(float) * NN;
    int*   offs = (int*)w;    w += sizeof(int) * (NN + 1);
    float* sums = (float*)w;  w += sizeof(float) * 2 * F;
    float* ac   = (float*)w;  w += sizeof(float) * 2 * F;
    int*   csrc = (int*)w;    w += sizeof(int) * NE;
    // union region: deg+cur (0.8 MB) live only during CSR build; buf0 (25.6 MB) after
    char* uni = w;
    int*   deg  = (int*)uni;
    int*   cur  = (int*)(uni + sizeof(int) * NN);
    float* buf0 = (float*)uni;

    const int B = 256;
    dim3 blk(B);

    k_init<<<dim3((NN + B - 1) / B), blk, 0, stream>>>(deg, pooled, sums);
    k_deg<<<dim3((NE + B - 1) / B), blk, 0, stream>>>(dst, deg);
    k_dinv<<<dim3((NN + B - 1) / B), blk, 0, stream>>>(deg, dinv);
    k_scan<<<dim3(1), dim3(1024), 0, stream>>>(deg, offs, cur);
    k_scatter<<<dim3((NE + B - 1) / B), blk, 0, stream>>>(src, dst, cur, csrc);

    dim3 gh((NN + 3) / 4);   // 25000 blocks, 1 wave per node

    // hop 1: x -> buf0   (buf0 overlaps deg/cur — CSR build is complete by now)
    k_hop<<<gh, blk, 0, stream>>>(offs, csrc, dinv, x, buf0);
    // hop 2: buf0 -> outh
    k_hop<<<gh, blk, 0, stream>>>(offs, csrc, dinv, buf0, outh);
    // hop 3: outh -> buf0
    k_hop<<<gh, blk, 0, stream>>>(offs, csrc, dinv, outh, buf0);

    // linear + relu + BN stats: buf0 -> outh(y)
    k_linear<<<dim3((NN + 63) / 64), blk, 0, stream>>>(buf0, W, b, outh, sums);
    k_bnp<<<dim3(1), dim3(64), 0, stream>>>(sums, gamma, beta, ac);
    k_normpool<<<dim3((NN + 255) / 256), blk, 0, stream>>>(outh, batch, ac, outh, pooled);
}

// Round 3
// 538.042 us; speedup vs baseline: 2.3315x; 1.4103x over previous
//
#include <hip/hip_runtime.h>

#define NN 100000
#define NE 1600000
#define F 64
#define NG 64
#define BN_EPS 1e-5f
#define SCAN_B 1024
#define NBLK ((NN + SCAN_B - 1) / SCAN_B)   // 98

__device__ __forceinline__ float fatomic_add(float* p, float v) {
    return unsafeAtomicAdd(p, v);   // native global_atomic_add_f32
}

// deg[i]=1 (self loop), zero pooled + sums
__global__ void k_init(int* __restrict__ deg, float* __restrict__ pooled,
                       float* __restrict__ sums) {
    int i = blockIdx.x * blockDim.x + threadIdx.x;
    if (i < NN) deg[i] = 1;
    if (i < NG * F) pooled[i] = 0.f;
    if (i < 2 * F) sums[i] = 0.f;
}

__global__ void k_deg(const int* __restrict__ dst, int* __restrict__ deg) {
    int e = blockIdx.x * blockDim.x + threadIdx.x;
    if (e < NE) atomicAdd(&deg[dst[e]], 1);
}

__global__ void k_dinv(const int* __restrict__ deg, float* __restrict__ dinv) {
    int i = blockIdx.x * blockDim.x + threadIdx.x;
    if (i < NN) dinv[i] = rsqrtf((float)deg[i]);
}

// pass 1: per-block sum of (deg-1)
__global__ __launch_bounds__(SCAN_B) void k_scan1(const int* __restrict__ deg,
                                                  int* __restrict__ bsum) {
    int t = threadIdx.x;
    int i = blockIdx.x * SCAN_B + t;
    int v = (i < NN) ? deg[i] - 1 : 0;
#pragma unroll
    for (int o = 32; o > 0; o >>= 1) v += __shfl_down(v, o, 64);
    __shared__ int ws[16];
    if ((t & 63) == 0) ws[t >> 6] = v;
    __syncthreads();
    if (t == 0) {
        int s = 0;
#pragma unroll
        for (int k = 0; k < 16; ++k) s += ws[k];
        bsum[blockIdx.x] = s;
    }
}

// pass 2: exclusive scan of the 98 block sums (single tiny block)
__global__ __launch_bounds__(128) void k_scan2(const int* __restrict__ bsum,
                                               int* __restrict__ bpre) {
    __shared__ int sh[128];
    int t = threadIdx.x;
    int v = (t < NBLK) ? bsum[t] : 0;
    sh[t] = v;
    __syncthreads();
    for (int off = 1; off < 128; off <<= 1) {
        int u = (t >= off) ? sh[t - off] : 0;
        __syncthreads();
        sh[t] += u;
        __syncthreads();
    }
    if (t < NBLK) bpre[t] = sh[t] - v;   // exclusive
}

// pass 3: block-local LDS scan + add block prefix; writes offs and cur
__global__ __launch_bounds__(SCAN_B) void k_scan3(const int* __restrict__ deg,
                                                  const int* __restrict__ bpre,
                                                  int* __restrict__ offs,
                                                  int* __restrict__ cur) {
    __shared__ int sh[SCAN_B];
    int t = threadIdx.x;
    int i = blockIdx.x * SCAN_B + t;
    int v = (i < NN) ? deg[i] - 1 : 0;
    sh[t] = v;
    __syncthreads();
    for (int off = 1; off < SCAN_B; off <<= 1) {
        int u = (t >= off) ? sh[t - off] : 0;
        __syncthreads();
        sh[t] += u;
        __syncthreads();
    }
    if (i < NN) {
        int o = bpre[blockIdx.x] + sh[t] - v;   // exclusive global prefix
        offs[i] = o;
        cur[i] = o;
    }
    if (blockIdx.x == 0 && t == 0) offs[NN] = NE;  // sum of in-degrees == NE
}

// scatter src index into CSR slot of its dst
__global__ void k_scatter(const int* __restrict__ src, const int* __restrict__ dst,
                          int* __restrict__ cur, int* __restrict__ csrc) {
    int e = blockIdx.x * blockDim.x + threadIdx.x;
    if (e >= NE) return;
    int pos = atomicAdd(&cur[dst[e]], 1);
    csrc[pos] = src[e];
}

// hout[n,:] = dinv[n]^2*hin[n,:] + sum_{s in N_in(n)} dinv[s]*dinv[n]*hin[s,:]
// one wave per node; 64 lanes = 64 features
__global__ __launch_bounds__(256) void k_hop(const int* __restrict__ offs,
                                             const int* __restrict__ csrc,
                                             const float* __restrict__ dinv,
                                             const float* __restrict__ hin,
                                             float* __restrict__ hout) {
    int n = blockIdx.x * 4 + (threadIdx.x >> 6);
    if (n >= NN) return;
    int f = threadIdx.x & 63;
    float dn = dinv[n];
    float acc = dn * dn * hin[(size_t)n * F + f];
    int e = offs[n], end = offs[n + 1];
    for (; e + 4 <= end; e += 4) {
        int s0 = csrc[e], s1 = csrc[e + 1], s2 = csrc[e + 2], s3 = csrc[e + 3];
        float w0 = dinv[s0], w1 = dinv[s1], w2 = dinv[s2], w3 = dinv[s3];
        float h0 = hin[(size_t)s0 * F + f];
        float h1 = hin[(size_t)s1 * F + f];
        float h2 = hin[(size_t)s2 * F + f];
        float h3 = hin[(size_t)s3 * F + f];
        acc += dn * (w0 * h0 + w1 * h1 + w2 * h2 + w3 * h3);
    }
    for (; e < end; ++e) {
        int s = csrc[e];
        acc += dn * dinv[s] * hin[(size_t)s * F + f];
    }
    hout[(size_t)n * F + f] = acc;
}

// y = relu(h @ W^T + b); accumulate per-feature sum/sumsq
__global__ __launch_bounds__(256) void k_linear(const float* __restrict__ h,
                                                const float* __restrict__ Wg,
                                                const float* __restrict__ bg,
                                                float* __restrict__ y,
                                                float* __restrict__ sums) {
    __shared__ float Wt[64][65];
    __shared__ float hrow[4][64];
    __shared__ float red[2][4][64];
    int tid = threadIdx.x;
    int j = tid & 63, nl = tid >> 6;
    for (int i = tid; i < 64 * 64; i += 256)
        Wt[i & 63][i >> 6] = Wg[i];
    float bj = bg[j];
    float lsum = 0.f, lsq = 0.f;
    int base = blockIdx.x * 64;
    for (int it = 0; it < 16; ++it) {
        int n0 = base + it * 4;
        __syncthreads();
        int nidx = n0 + nl;
        hrow[nl][j] = (nidx < NN) ? h[(size_t)nidx * 64 + j] : 0.f;
        __syncthreads();
        int n = n0 + nl;
        if (n < NN) {
            float acc = bj;
#pragma unroll
            for (int ff = 0; ff < 64; ++ff)
                acc = fmaf(hrow[nl][ff], Wt[ff][j], acc);
            acc = fmaxf(acc, 0.f);
            y[(size_t)n * 64 + j] = acc;
            lsum += acc; lsq += acc * acc;
        }
    }
    red[0][nl][j] = lsum;
    red[1][nl][j] = lsq;
    __syncthreads();
    if (nl == 0) {
        float s = red[0][0][j] + red[0][1][j] + red[0][2][j] + red[0][3][j];
        float q = red[1][0][j] + red[1][1][j] + red[1][2][j] + red[1][3][j];
        fatomic_add(&sums[j], s);
        fatomic_add(&sums[64 + j], q);
    }
}

__global__ void k_bnp(const float* __restrict__ sums, const float* __restrict__ gamma,
                      const float* __restrict__ beta, float* __restrict__ ac) {
    int j = threadIdx.x;   // 64
    float mean = sums[j] * (1.0f / NN);
    float var = sums[64 + j] * (1.0f / NN) - mean * mean;
    float rinv = rsqrtf(var + BN_EPS);
    float a = gamma[j] * rinv;
    ac[j] = a;
    ac[64 + j] = beta[j] - mean * a;
}

__global__ __launch_bounds__(256) void k_normpool(const float* __restrict__ y,
                                                  const int* __restrict__ batch,
                                                  const float* __restrict__ ac,
                                                  float* __restrict__ outh,
                                                  float* __restrict__ pooled) {
    int tid = threadIdx.x;
    int j = tid & 63, nl = tid >> 6;
    float a = ac[j], c = ac[64 + j];
    int base = blockIdx.x * 256;
    int curg = -1;
    float acc = 0.f;
    for (int it = 0; it < 64; ++it) {
        int n = base + it * 4 + nl;
        if (n >= NN) break;
        int g = batch[n];
        float v = fmaf(y[(size_t)n * 64 + j], a, c);
        outh[(size_t)n * 64 + j] = v;
        if (g != curg) {
            if (curg >= 0) fatomic_add(&pooled[curg * 64 + j], acc);
            curg = g; acc = 0.f;
        }
        acc += v;
    }
    if (curg >= 0) fatomic_add(&pooled[curg * 64 + j], acc);
}

extern "C" void kernel_launch(void* const* d_in, const int* in_sizes, int n_in,
                              void* d_out, int out_size, void* d_ws, size_t ws_size,
                              hipStream_t stream) {
    const float* x     = (const float*)d_in[0];
    const int*   ei    = (const int*)d_in[1];
    const int*   batch = (const int*)d_in[2];
    const float* W     = (const float*)d_in[3];
    const float* b     = (const float*)d_in[4];
    const float* gamma = (const float*)d_in[5];
    const float* beta  = (const float*)d_in[6];
    const int* src = ei;
    const int* dst = ei + NE;

    float* pooled = (float*)d_out;
    float* outh   = (float*)d_out + NG * F;   // also ping-pong buffer

    char* w = (char*)d_ws;
    float* dinv = (float*)w;  w += sizeof(float) * NN;
    int*   offs = (int*)w;    w += sizeof(int) * (NN + 1);
    float* sums = (float*)w;  w += sizeof(float) * 2 * F;
    float* ac   = (float*)w;  w += sizeof(float) * 2 * F;
    int*   bsum = (int*)w;    w += sizeof(int) * 128;
    int*   bpre = (int*)w;    w += sizeof(int) * 128;
    int*   csrc = (int*)w;    w += sizeof(int) * NE;
    // union region: deg+cur (0.8 MB) live only during CSR build; buf0 (25.6 MB) after
    char* uni = w;
    int*   deg  = (int*)uni;
    int*   cur  = (int*)(uni + sizeof(int) * NN);
    float* buf0 = (float*)uni;

    const int B = 256;
    dim3 blk(B);

    k_init<<<dim3((NN + B - 1) / B), blk, 0, stream>>>(deg, pooled, sums);
    k_deg<<<dim3((NE + B - 1) / B), blk, 0, stream>>>(dst, deg);
    k_dinv<<<dim3((NN + B - 1) / B), blk, 0, stream>>>(deg, dinv);
    k_scan1<<<dim3(NBLK), dim3(SCAN_B), 0, stream>>>(deg, bsum);
    k_scan2<<<dim3(1), dim3(128), 0, stream>>>(bsum, bpre);
    k_scan3<<<dim3(NBLK), dim3(SCAN_B), 0, stream>>>(deg, bpre, offs, cur);
    k_scatter<<<dim3((NE + B - 1) / B), blk, 0, stream>>>(src, dst, cur, csrc);

    dim3 gh((NN + 3) / 4);   // 25000 blocks, 1 wave per node

    // hop 1: x -> buf0   (buf0 overlaps deg/cur — CSR build is complete by now)
    k_hop<<<gh, blk, 0, stream>>>(offs, csrc, dinv, x, buf0);
    // hop 2: buf0 -> outh
    k_hop<<<gh, blk, 0, stream>>>(offs, csrc, dinv, buf0, outh);
    // hop 3: outh -> buf0
    k_hop<<<gh, blk, 0, stream>>>(offs, csrc, dinv, outh, buf0);

    // linear + relu + BN stats: buf0 -> outh(y)
    k_linear<<<dim3((NN + 63) / 64), blk, 0, stream>>>(buf0, W, b, outh, sums);
    k_bnp<<<dim3(1), dim3(64), 0, stream>>>(sums, gamma, beta, ac);
    k_normpool<<<dim3((NN + 255) / 256), blk, 0, stream>>>(outh, batch, ac, outh, pooled);
}

// Round 4
// 500.983 us; speedup vs baseline: 2.5040x; 1.0740x over previous
//
#include <hip/hip_runtime.h>

#define NN 100000
#define NE 1600000
#define F 64
#define NG 64
#define BN_EPS 1e-5f
#define SCAN_B 1024
#define NBLK ((NN + SCAN_B - 1) / SCAN_B)   // 98
#define NCH 8
#define NPC (NN / NCH)                       // 12500 nodes per chunk

__device__ __forceinline__ float fatomic_add(float* p, float v) {
    return unsafeAtomicAdd(p, v);   // native global_atomic_add_f32
}

// deg[i]=1 (self loop), zero pooled + sums
__global__ void k_init(int* __restrict__ deg, float* __restrict__ pooled,
                       float* __restrict__ sums) {
    int i = blockIdx.x * blockDim.x + threadIdx.x;
    if (i < NN) deg[i] = 1;
    if (i < NG * F) pooled[i] = 0.f;
    if (i < 2 * F) sums[i] = 0.f;
}

__global__ void k_deg(const int* __restrict__ dst, int* __restrict__ deg) {
    int e = blockIdx.x * blockDim.x + threadIdx.x;
    if (e < NE) atomicAdd(&deg[dst[e]], 1);
}

// dinv = deg^-1/2, dn2 = 1/deg, sq = deg^1/2
__global__ void k_prec(const int* __restrict__ deg, float* __restrict__ dinv,
                       float* __restrict__ dn2, float* __restrict__ sq) {
    int i = blockIdx.x * blockDim.x + threadIdx.x;
    if (i >= NN) return;
    float d = (float)deg[i];
    float r = rsqrtf(d);
    dinv[i] = r;
    dn2[i] = r * r;
    sq[i] = d * r;   // sqrt(deg)
}

// u0 = dinv (.) x
__global__ void k_u0(const float* __restrict__ x, const float* __restrict__ dinv,
                     float* __restrict__ u) {
    int idx = blockIdx.x * blockDim.x + threadIdx.x;   // NN*F
    if (idx >= NN * F) return;
    u[idx] = dinv[idx >> 6] * x[idx];
}

// pass 1: per-block sum of (deg-1)
__global__ __launch_bounds__(SCAN_B) void k_scan1(const int* __restrict__ deg,
                                                  int* __restrict__ bsum) {
    int t = threadIdx.x;
    int i = blockIdx.x * SCAN_B + t;
    int v = (i < NN) ? deg[i] - 1 : 0;
#pragma unroll
    for (int o = 32; o > 0; o >>= 1) v += __shfl_down(v, o, 64);
    __shared__ int ws[16];
    if ((t & 63) == 0) ws[t >> 6] = v;
    __syncthreads();
    if (t == 0) {
        int s = 0;
#pragma unroll
        for (int k = 0; k < 16; ++k) s += ws[k];
        bsum[blockIdx.x] = s;
    }
}

// pass 2: exclusive scan of the 98 block sums
__global__ __launch_bounds__(128) void k_scan2(const int* __restrict__ bsum,
                                               int* __restrict__ bpre) {
    __shared__ int sh[128];
    int t = threadIdx.x;
    int v = (t < NBLK) ? bsum[t] : 0;
    sh[t] = v;
    __syncthreads();
    for (int off = 1; off < 128; off <<= 1) {
        int u = (t >= off) ? sh[t - off] : 0;
        __syncthreads();
        sh[t] += u;
        __syncthreads();
    }
    if (t < NBLK) bpre[t] = sh[t] - v;   // exclusive
}

// pass 3: block-local scan + block prefix; writes offs and cur
__global__ __launch_bounds__(SCAN_B) void k_scan3(const int* __restrict__ deg,
                                                  const int* __restrict__ bpre,
                                                  int* __restrict__ offs,
                                                  int* __restrict__ cur) {
    __shared__ int sh[SCAN_B];
    int t = threadIdx.x;
    int i = blockIdx.x * SCAN_B + t;
    int v = (i < NN) ? deg[i] - 1 : 0;
    sh[t] = v;
    __syncthreads();
    for (int off = 1; off < SCAN_B; off <<= 1) {
        int u = (t >= off) ? sh[t - off] : 0;
        __syncthreads();
        sh[t] += u;
        __syncthreads();
    }
    if (i < NN) {
        int o = bpre[blockIdx.x] + sh[t] - v;
        offs[i] = o;
        cur[i] = o;
    }
    if (blockIdx.x == 0 && t == 0) offs[NN] = NE;
}

// XCD-localized chunked scatter: block b handles node-chunk b%8 so each csrc
// line is written from a single XCD's L2 (kills the 16x write amplification).
__global__ void k_scatter(const int* __restrict__ src, const int* __restrict__ dst,
                          int* __restrict__ cur, int* __restrict__ csrc) {
    int ch = blockIdx.x & (NCH - 1);
    int seg = blockIdx.x >> 3;
    int e = seg * 256 + threadIdx.x;
    if (e >= NE) return;
    int d = dst[e];
    int lo = ch * NPC;
    if (d < lo || d >= lo + NPC) return;
    int pos = atomicAdd(&cur[d], 1);
    csrc[pos] = src[e];
}

// u_out[n,:] = dn2[n] * (u_in[n,:] + sum_{s in Nin(n)} u_in[s,:])
__global__ __launch_bounds__(256) void k_hop(const int* __restrict__ offs,
                                             const int* __restrict__ csrc,
                                             const float* __restrict__ dn2,
                                             const float* __restrict__ uin,
                                             float* __restrict__ uout) {
    int n = blockIdx.x * 4 + (threadIdx.x >> 6);
    if (n >= NN) return;
    int f = threadIdx.x & 63;
    float acc = uin[(size_t)n * F + f];
    int e = offs[n], end = offs[n + 1];
    for (; e + 8 <= end; e += 8) {
        int s0 = csrc[e],     s1 = csrc[e + 1], s2 = csrc[e + 2], s3 = csrc[e + 3];
        int s4 = csrc[e + 4], s5 = csrc[e + 5], s6 = csrc[e + 6], s7 = csrc[e + 7];
        float h0 = uin[(size_t)s0 * F + f];
        float h1 = uin[(size_t)s1 * F + f];
        float h2 = uin[(size_t)s2 * F + f];
        float h3 = uin[(size_t)s3 * F + f];
        float h4 = uin[(size_t)s4 * F + f];
        float h5 = uin[(size_t)s5 * F + f];
        float h6 = uin[(size_t)s6 * F + f];
        float h7 = uin[(size_t)s7 * F + f];
        acc += ((h0 + h1) + (h2 + h3)) + ((h4 + h5) + (h6 + h7));
    }
    for (; e < end; ++e)
        acc += uin[(size_t)csrc[e] * F + f];
    uout[(size_t)n * F + f] = dn2[n] * acc;
}

// y = relu((u*sq) @ W^T + b); accumulate per-feature sum/sumsq
__global__ __launch_bounds__(256) void k_linear(const float* __restrict__ u,
                                                const float* __restrict__ sq,
                                                const float* __restrict__ Wg,
                                                const float* __restrict__ bg,
                                                float* __restrict__ y,
                                                float* __restrict__ sums) {
    __shared__ float Wt[64][65];
    __shared__ float hrow[4][64];
    __shared__ float red[2][4][64];
    int tid = threadIdx.x;
    int j = tid & 63, nl = tid >> 6;
    for (int i = tid; i < 64 * 64; i += 256)
        Wt[i & 63][i >> 6] = Wg[i];
    float bj = bg[j];
    float lsum = 0.f, lsq = 0.f;
    int base = blockIdx.x * 64;
    for (int it = 0; it < 16; ++it) {
        int n0 = base + it * 4;
        __syncthreads();
        int nidx = n0 + nl;
        hrow[nl][j] = (nidx < NN) ? u[(size_t)nidx * 64 + j] * sq[nidx] : 0.f;
        __syncthreads();
        int n = n0 + nl;
        if (n < NN) {
            float acc = bj;
#pragma unroll
            for (int ff = 0; ff < 64; ++ff)
                acc = fmaf(hrow[nl][ff], Wt[ff][j], acc);
            acc = fmaxf(acc, 0.f);
            y[(size_t)n * 64 + j] = acc;
            lsum += acc; lsq += acc * acc;
        }
    }
    red[0][nl][j] = lsum;
    red[1][nl][j] = lsq;
    __syncthreads();
    if (nl == 0) {
        float s = red[0][0][j] + red[0][1][j] + red[0][2][j] + red[0][3][j];
        float q = red[1][0][j] + red[1][1][j] + red[1][2][j] + red[1][3][j];
        fatomic_add(&sums[j], s);
        fatomic_add(&sums[64 + j], q);
    }
}

__global__ void k_bnp(const float* __restrict__ sums, const float* __restrict__ gamma,
                      const float* __restrict__ beta, float* __restrict__ ac) {
    int j = threadIdx.x;   // 64
    float mean = sums[j] * (1.0f / NN);
    float var = sums[64 + j] * (1.0f / NN) - mean * mean;
    float rinv = rsqrtf(var + BN_EPS);
    float a = gamma[j] * rinv;
    ac[j] = a;
    ac[64 + j] = beta[j] - mean * a;
}

__global__ __launch_bounds__(256) void k_normpool(const float* __restrict__ y,
                                                  const int* __restrict__ batch,
                                                  const float* __restrict__ ac,
                                                  float* __restrict__ outh,
                                                  float* __restrict__ pooled) {
    int tid = threadIdx.x;
    int j = tid & 63, nl = tid >> 6;
    float a = ac[j], c = ac[64 + j];
    int base = blockIdx.x * 256;
    int curg = -1;
    float acc = 0.f;
    for (int it = 0; it < 64; ++it) {
        int n = base + it * 4 + nl;
        if (n >= NN) break;
        int g = batch[n];
        float v = fmaf(y[(size_t)n * 64 + j], a, c);
        outh[(size_t)n * 64 + j] = v;
        if (g != curg) {
            if (curg >= 0) fatomic_add(&pooled[curg * 64 + j], acc);
            curg = g; acc = 0.f;
        }
        acc += v;
    }
    if (curg >= 0) fatomic_add(&pooled[curg * 64 + j], acc);
}

extern "C" void kernel_launch(void* const* d_in, const int* in_sizes, int n_in,
                              void* d_out, int out_size, void* d_ws, size_t ws_size,
                              hipStream_t stream) {
    const float* x     = (const float*)d_in[0];
    const int*   ei    = (const int*)d_in[1];
    const int*   batch = (const int*)d_in[2];
    const float* W     = (const float*)d_in[3];
    const float* b     = (const float*)d_in[4];
    const float* gamma = (const float*)d_in[5];
    const float* beta  = (const float*)d_in[6];
    const int* src = ei;
    const int* dst = ei + NE;

    float* pooled = (float*)d_out;
    float* outh   = (float*)d_out + NG * F;   // ping-pong buffer B

    char* w = (char*)d_ws;
    float* dinv = (float*)w;  w += sizeof(float) * NN;
    float* dn2  = (float*)w;  w += sizeof(float) * NN;
    float* sq   = (float*)w;  w += sizeof(float) * NN;
    int*   offs = (int*)w;    w += sizeof(int) * (NN + 1);
    float* sums = (float*)w;  w += sizeof(float) * 2 * F;
    float* ac   = (float*)w;  w += sizeof(float) * 2 * F;
    int*   bsum = (int*)w;    w += sizeof(int) * 128;
    int*   bpre = (int*)w;    w += sizeof(int) * 128;
    int*   csrc = (int*)w;    w += sizeof(int) * NE;
    // union: deg+cur (0.8 MB, CSR build only) | buf0 (25.6 MB, hops)
    char* uni = w;
    int*   deg  = (int*)uni;
    int*   cur  = (int*)(uni + sizeof(int) * NN);
    float* buf0 = (float*)uni;   // ping-pong buffer A

    const int B = 256;
    dim3 blk(B);

    k_init<<<dim3((NN + B - 1) / B), blk, 0, stream>>>(deg, pooled, sums);
    k_deg<<<dim3((NE + B - 1) / B), blk, 0, stream>>>(dst, deg);
    k_prec<<<dim3((NN + B - 1) / B), blk, 0, stream>>>(deg, dinv, dn2, sq);
    k_scan1<<<dim3(NBLK), dim3(SCAN_B), 0, stream>>>(deg, bsum);
    k_scan2<<<dim3(1), dim3(128), 0, stream>>>(bsum, bpre);
    k_scan3<<<dim3(NBLK), dim3(SCAN_B), 0, stream>>>(deg, bpre, offs, cur);
    k_scatter<<<dim3(((NE + B - 1) / B) * NCH), blk, 0, stream>>>(src, dst, cur, csrc);

    // u0 = dinv.x -> outh
    k_u0<<<dim3((NN * F) / B), blk, 0, stream>>>(x, dinv, outh);

    dim3 gh((NN + 3) / 4);   // 25000 blocks, 1 wave per node
    // hop 1: outh -> buf0  (buf0 overlaps deg/cur — CSR build complete)
    k_hop<<<gh, blk, 0, stream>>>(offs, csrc, dn2, outh, buf0);
    // hop 2: buf0 -> outh
    k_hop<<<gh, blk, 0, stream>>>(offs, csrc, dn2, buf0, outh);
    // hop 3: outh -> buf0
    k_hop<<<gh, blk, 0, stream>>>(offs, csrc, dn2, outh, buf0);

    // linear + relu + BN stats: (buf0 * sq) -> outh(y)
    k_linear<<<dim3((NN + 63) / 64), blk, 0, stream>>>(buf0, sq, W, b, outh, sums);
    k_bnp<<<dim3(1), dim3(64), 0, stream>>>(sums, gamma, beta, ac);
    k_normpool<<<dim3((NN + 255) / 256), blk, 0, stream>>>(outh, batch, ac, outh, pooled);
}

// Round 5
// 466.942 us; speedup vs baseline: 2.6865x; 1.0729x over previous
//
#include <hip/hip_runtime.h>
#include <hip/hip_fp16.h>

#define NN 100000
#define NE 1600000
#define F 64
#define NG 64
#define BN_EPS 1e-5f
#define SCAN_B 1024
#define NBLK ((NN + SCAN_B - 1) / SCAN_B)   // 98
#define NCH 8
#define NPC (NN / NCH)                       // 12500 nodes per chunk

__device__ __forceinline__ float fatomic_add(float* p, float v) {
    return unsafeAtomicAdd(p, v);   // native global_atomic_add_f32
}

// deg[i]=1 (self loop), zero pooled + sums
__global__ void k_init(int* __restrict__ deg, float* __restrict__ pooled,
                       float* __restrict__ sums) {
    int i = blockIdx.x * blockDim.x + threadIdx.x;
    if (i < NN) deg[i] = 1;
    if (i < NG * F) pooled[i] = 0.f;
    if (i < 2 * F) sums[i] = 0.f;
}

__global__ void k_deg(const int* __restrict__ dst, int* __restrict__ deg) {
    int e = blockIdx.x * blockDim.x + threadIdx.x;
    if (e < NE) atomicAdd(&deg[dst[e]], 1);
}

// dinv = deg^-1/2, dn2 = 1/deg, sq = deg^1/2
__global__ void k_prec(const int* __restrict__ deg, float* __restrict__ dinv,
                       float* __restrict__ dn2, float* __restrict__ sq) {
    int i = blockIdx.x * blockDim.x + threadIdx.x;
    if (i >= NN) return;
    float d = (float)deg[i];
    float r = rsqrtf(d);
    dinv[i] = r;
    dn2[i] = r * r;
    sq[i] = d * r;   // sqrt(deg)
}

// u0 = dinv (.) x   (fp32 -> fp16, 2 elems/thread)
__global__ void k_u0(const float2* __restrict__ x2, const float* __restrict__ dinv,
                     __half2* __restrict__ u2) {
    int i = blockIdx.x * blockDim.x + threadIdx.x;   // NN*F/2
    if (i >= NN * F / 2) return;
    float2 v = x2[i];
    float d = dinv[i >> 5];                           // node = (2i)>>6
    u2[i] = __floats2half2_rn(v.x * d, v.y * d);
}

// pass 1: per-block sum of (deg-1)
__global__ __launch_bounds__(SCAN_B) void k_scan1(const int* __restrict__ deg,
                                                  int* __restrict__ bsum) {
    int t = threadIdx.x;
    int i = blockIdx.x * SCAN_B + t;
    int v = (i < NN) ? deg[i] - 1 : 0;
#pragma unroll
    for (int o = 32; o > 0; o >>= 1) v += __shfl_down(v, o, 64);
    __shared__ int ws[16];
    if ((t & 63) == 0) ws[t >> 6] = v;
    __syncthreads();
    if (t == 0) {
        int s = 0;
#pragma unroll
        for (int k = 0; k < 16; ++k) s += ws[k];
        bsum[blockIdx.x] = s;
    }
}

// pass 2: exclusive scan of the 98 block sums
__global__ __launch_bounds__(128) void k_scan2(const int* __restrict__ bsum,
                                               int* __restrict__ bpre) {
    __shared__ int sh[128];
    int t = threadIdx.x;
    int v = (t < NBLK) ? bsum[t] : 0;
    sh[t] = v;
    __syncthreads();
    for (int off = 1; off < 128; off <<= 1) {
        int u = (t >= off) ? sh[t - off] : 0;
        __syncthreads();
        sh[t] += u;
        __syncthreads();
    }
    if (t < NBLK) bpre[t] = sh[t] - v;   // exclusive
}

// pass 3: block-local scan + block prefix; writes offs and cur
__global__ __launch_bounds__(SCAN_B) void k_scan3(const int* __restrict__ deg,
                                                  const int* __restrict__ bpre,
                                                  int* __restrict__ offs,
                                                  int* __restrict__ cur) {
    __shared__ int sh[SCAN_B];
    int t = threadIdx.x;
    int i = blockIdx.x * SCAN_B + t;
    int v = (i < NN) ? deg[i] - 1 : 0;
    sh[t] = v;
    __syncthreads();
    for (int off = 1; off < SCAN_B; off <<= 1) {
        int u = (t >= off) ? sh[t - off] : 0;
        __syncthreads();
        sh[t] += u;
        __syncthreads();
    }
    if (i < NN) {
        int o = bpre[blockIdx.x] + sh[t] - v;
        offs[i] = o;
        cur[i] = o;
    }
    if (blockIdx.x == 0 && t == 0) offs[NN] = NE;
}

// XCD-localized chunked scatter (kills partial-line write amplification)
__global__ void k_scatter(const int* __restrict__ src, const int* __restrict__ dst,
                          int* __restrict__ cur, int* __restrict__ csrc) {
    int ch = blockIdx.x & (NCH - 1);
    int seg = blockIdx.x >> 3;
    int e = seg * 256 + threadIdx.x;
    if (e >= NE) return;
    int d = dst[e];
    int lo = ch * NPC;
    if (d < lo || d >= lo + NPC) return;
    int pos = atomicAdd(&cur[d], 1);
    csrc[pos] = src[e];
}

// u_out[n,:] = dn2[n] * (u_in[n,:] + sum_{s in Nin(n)} u_in[s,:])   fp16 rows
__global__ __launch_bounds__(256) void k_hop(const int* __restrict__ offs,
                                             const int* __restrict__ csrc,
                                             const float* __restrict__ dn2,
                                             const __half* __restrict__ uin,
                                             __half* __restrict__ uout) {
    int n = blockIdx.x * 4 + (threadIdx.x >> 6);
    if (n >= NN) return;
    int f = threadIdx.x & 63;
    float acc = __half2float(uin[n * F + f]);
    int e = offs[n], end = offs[n + 1];
    for (; e + 8 <= end; e += 8) {
        int s0 = csrc[e],     s1 = csrc[e + 1], s2 = csrc[e + 2], s3 = csrc[e + 3];
        int s4 = csrc[e + 4], s5 = csrc[e + 5], s6 = csrc[e + 6], s7 = csrc[e + 7];
        float h0 = __half2float(uin[s0 * F + f]);
        float h1 = __half2float(uin[s1 * F + f]);
        float h2 = __half2float(uin[s2 * F + f]);
        float h3 = __half2float(uin[s3 * F + f]);
        float h4 = __half2float(uin[s4 * F + f]);
        float h5 = __half2float(uin[s5 * F + f]);
        float h6 = __half2float(uin[s6 * F + f]);
        float h7 = __half2float(uin[s7 * F + f]);
        acc += ((h0 + h1) + (h2 + h3)) + ((h4 + h5) + (h6 + h7));
    }
    for (; e < end; ++e)
        acc += __half2float(uin[csrc[e] * F + f]);
    uout[n * F + f] = __float2half(dn2[n] * acc);
}

// y = relu((u*sq) @ W^T + b)  (fp16 in, fp16 out); per-feature sum/sumsq stats
__global__ __launch_bounds__(256) void k_linear(const __half* __restrict__ u,
                                                const float* __restrict__ sq,
                                                const float* __restrict__ Wg,
                                                const float* __restrict__ bg,
                                                __half* __restrict__ y,
                                                float* __restrict__ sums) {
    __shared__ float Wt[64][65];
    __shared__ float hrow[4][64];
    __shared__ float red[2][4][64];
    int tid = threadIdx.x;
    int j = tid & 63, nl = tid >> 6;
    for (int i = tid; i < 64 * 64; i += 256)
        Wt[i & 63][i >> 6] = Wg[i];
    float bj = bg[j];
    float lsum = 0.f, lsq = 0.f;
    int base = blockIdx.x * 64;
    __syncthreads();                       // Wt ready; hrow slots are wave-local
    for (int it = 0; it < 16; ++it) {
        int n = base + it * 4 + nl;
        if (n < NN) {
            hrow[nl][j] = __half2float(u[n * 64 + j]) * sq[n];
            float acc = bj;
#pragma unroll
            for (int ff = 0; ff < 64; ++ff)
                acc = fmaf(hrow[nl][ff], Wt[ff][j], acc);
            acc = fmaxf(acc, 0.f);
            y[n * 64 + j] = __float2half(acc);
            lsum += acc; lsq += acc * acc;
        }
    }
    red[0][nl][j] = lsum;
    red[1][nl][j] = lsq;
    __syncthreads();
    if (nl == 0) {
        float s = red[0][0][j] + red[0][1][j] + red[0][2][j] + red[0][3][j];
        float q = red[1][0][j] + red[1][1][j] + red[1][2][j] + red[1][3][j];
        fatomic_add(&sums[j], s);
        fatomic_add(&sums[64 + j], q);
    }
}

__global__ void k_bnp(const float* __restrict__ sums, const float* __restrict__ gamma,
                      const float* __restrict__ beta, float* __restrict__ ac) {
    int j = threadIdx.x;   // 64
    float mean = sums[j] * (1.0f / NN);
    float var = sums[64 + j] * (1.0f / NN) - mean * mean;
    float rinv = rsqrtf(var + BN_EPS);
    float a = gamma[j] * rinv;
    ac[j] = a;
    ac[64 + j] = beta[j] - mean * a;
}

__global__ __launch_bounds__(256) void k_normpool(const __half* __restrict__ y,
                                                  const int* __restrict__ batch,
                                                  const float* __restrict__ ac,
                                                  float* __restrict__ outh,
                                                  float* __restrict__ pooled) {
    int tid = threadIdx.x;
    int j = tid & 63, nl = tid >> 6;
    float a = ac[j], c = ac[64 + j];
    int base = blockIdx.x * 256;
    int curg = -1;
    float acc = 0.f;
    for (int it = 0; it < 64; ++it) {
        int n = base + it * 4 + nl;
        if (n >= NN) break;
        int g = batch[n];
        float v = fmaf(__half2float(y[n * 64 + j]), a, c);
        outh[(size_t)n * 64 + j] = v;
        if (g != curg) {
            if (curg >= 0) fatomic_add(&pooled[curg * 64 + j], acc);
            curg = g; acc = 0.f;
        }
        acc += v;
    }
    if (curg >= 0) fatomic_add(&pooled[curg * 64 + j], acc);
}

extern "C" void kernel_launch(void* const* d_in, const int* in_sizes, int n_in,
                              void* d_out, int out_size, void* d_ws, size_t ws_size,
                              hipStream_t stream) {
    const float* x     = (const float*)d_in[0];
    const int*   ei    = (const int*)d_in[1];
    const int*   batch = (const int*)d_in[2];
    const float* W     = (const float*)d_in[3];
    const float* b     = (const float*)d_in[4];
    const float* gamma = (const float*)d_in[5];
    const float* beta  = (const float*)d_in[6];
    const int* src = ei;
    const int* dst = ei + NE;

    float* pooled = (float*)d_out;
    float* outh   = (float*)d_out + NG * F;

    char* w = (char*)d_ws;
    float* dinv = (float*)w;  w += sizeof(float) * NN;
    float* dn2  = (float*)w;  w += sizeof(float) * NN;
    float* sq   = (float*)w;  w += sizeof(float) * NN;
    int*   offs = (int*)w;    w += sizeof(int) * (NN + 1);
    float* sums = (float*)w;  w += sizeof(float) * 2 * F;
    float* ac   = (float*)w;  w += sizeof(float) * 2 * F;
    int*   bsum = (int*)w;    w += sizeof(int) * 128;
    int*   bpre = (int*)w;    w += sizeof(int) * 128;
    int*   csrc = (int*)w;    w += sizeof(int) * NE;
    // union: deg+cur (0.8 MB, CSR build only) | ubufA+ubufB (25.6 MB, hops on)
    char* uni = w;
    int*    deg   = (int*)uni;
    int*    cur   = (int*)(uni + sizeof(int) * NN);
    __half* ubufA = (__half*)uni;
    __half* ubufB = (__half*)(uni + sizeof(__half) * NN * F);

    const int B = 256;
    dim3 blk(B);

    k_init<<<dim3((NN + B - 1) / B), blk, 0, stream>>>(deg, pooled, sums);
    k_deg<<<dim3((NE + B - 1) / B), blk, 0, stream>>>(dst, deg);
    k_prec<<<dim3((NN + B - 1) / B), blk, 0, stream>>>(deg, dinv, dn2, sq);
    k_scan1<<<dim3(NBLK), dim3(SCAN_B), 0, stream>>>(deg, bsum);
    k_scan2<<<dim3(1), dim3(128), 0, stream>>>(bsum, bpre);
    k_scan3<<<dim3(NBLK), dim3(SCAN_B), 0, stream>>>(deg, bpre, offs, cur);
    k_scatter<<<dim3(((NE + B - 1) / B) * NCH), blk, 0, stream>>>(src, dst, cur, csrc);

    // u0 = dinv.x -> ubufA  (deg/cur dead from here on)
    k_u0<<<dim3((NN * F / 2 + B - 1) / B), blk, 0, stream>>>((const float2*)x, dinv, (__half2*)ubufA);

    dim3 gh((NN + 3) / 4);   // 25000 blocks, 1 wave per node
    k_hop<<<gh, blk, 0, stream>>>(offs, csrc, dn2, ubufA, ubufB);   // hop 1
    k_hop<<<gh, blk, 0, stream>>>(offs, csrc, dn2, ubufB, ubufA);   // hop 2
    k_hop<<<gh, blk, 0, stream>>>(offs, csrc, dn2, ubufA, ubufB);   // hop 3

    // linear + relu + BN stats: (ubufB * sq) -> y in ubufA (u2 dead)
    __half* yh = ubufA;
    k_linear<<<dim3((NN + 63) / 64), blk, 0, stream>>>(ubufB, sq, W, b, yh, sums);
    k_bnp<<<dim3(1), dim3(64), 0, stream>>>(sums, gamma, beta, ac);
    k_normpool<<<dim3((NN + 255) / 256), blk, 0, stream>>>(yh, batch, ac, outh, pooled);
}

// Round 6
// 459.891 us; speedup vs baseline: 2.7277x; 1.0153x over previous
//
#include <hip/hip_runtime.h>
#include <hip/hip_fp16.h>

#define NN 100000
#define NE 1600000
#define F 64
#define NG 64
#define BN_EPS 1e-5f
#define SCAN_B 1024
#define NBLK ((NN + SCAN_B - 1) / SCAN_B)   // 98
#define NCH 8
#define NPC (NN / NCH)                       // 12500 nodes per chunk

typedef _Float16 half8 __attribute__((ext_vector_type(8)));
typedef float f32x4 __attribute__((ext_vector_type(4)));

__device__ __forceinline__ float fatomic_add(float* p, float v) {
    return unsafeAtomicAdd(p, v);   // native global_atomic_add_f32
}

// deg[i]=1 (self loop), zero pooled + sums
__global__ void k_init(int* __restrict__ deg, float* __restrict__ pooled,
                       float* __restrict__ sums) {
    int i = blockIdx.x * blockDim.x + threadIdx.x;
    if (i < NN) deg[i] = 1;
    if (i < NG * F) pooled[i] = 0.f;
    if (i < 2 * F) sums[i] = 0.f;
}

__global__ void k_deg(const int* __restrict__ dst, int* __restrict__ deg) {
    int e = blockIdx.x * blockDim.x + threadIdx.x;
    if (e < NE) atomicAdd(&deg[dst[e]], 1);
}

// dinv = deg^-1/2, dn2 = 1/deg
__global__ void k_prec(const int* __restrict__ deg, float* __restrict__ dinv,
                       float* __restrict__ dn2) {
    int i = blockIdx.x * blockDim.x + threadIdx.x;
    if (i >= NN) return;
    float d = (float)deg[i];
    float r = rsqrtf(d);
    dinv[i] = r;
    dn2[i] = r * r;
}

// W (f32, 64x64) -> Wh (fp16)
__global__ void k_wh(const float* __restrict__ Wg, __half* __restrict__ Wh) {
    int i = blockIdx.x * blockDim.x + threadIdx.x;
    if (i < F * F) Wh[i] = __float2half(Wg[i]);
}

// u0 = dinv (.) x   (fp32 -> fp16, 2 elems/thread)
__global__ void k_u0(const float2* __restrict__ x2, const float* __restrict__ dinv,
                     __half2* __restrict__ u2) {
    int i = blockIdx.x * blockDim.x + threadIdx.x;   // NN*F/2
    if (i >= NN * F / 2) return;
    float2 v = x2[i];
    float d = dinv[i >> 5];                           // node = (2i)>>6
    u2[i] = __floats2half2_rn(v.x * d, v.y * d);
}

// pass 1: per-block sum of (deg-1)
__global__ __launch_bounds__(SCAN_B) void k_scan1(const int* __restrict__ deg,
                                                  int* __restrict__ bsum) {
    int t = threadIdx.x;
    int i = blockIdx.x * SCAN_B + t;
    int v = (i < NN) ? deg[i] - 1 : 0;
#pragma unroll
    for (int o = 32; o > 0; o >>= 1) v += __shfl_down(v, o, 64);
    __shared__ int ws[16];
    if ((t & 63) == 0) ws[t >> 6] = v;
    __syncthreads();
    if (t == 0) {
        int s = 0;
#pragma unroll
        for (int k = 0; k < 16; ++k) s += ws[k];
        bsum[blockIdx.x] = s;
    }
}

// pass 2: exclusive scan of the 98 block sums
__global__ __launch_bounds__(128) void k_scan2(const int* __restrict__ bsum,
                                               int* __restrict__ bpre) {
    __shared__ int sh[128];
    int t = threadIdx.x;
    int v = (t < NBLK) ? bsum[t] : 0;
    sh[t] = v;
    __syncthreads();
    for (int off = 1; off < 128; off <<= 1) {
        int u = (t >= off) ? sh[t - off] : 0;
        __syncthreads();
        sh[t] += u;
        __syncthreads();
    }
    if (t < NBLK) bpre[t] = sh[t] - v;   // exclusive
}

// pass 3: block-local scan + block prefix; writes offs and cur
__global__ __launch_bounds__(SCAN_B) void k_scan3(const int* __restrict__ deg,
                                                  const int* __restrict__ bpre,
                                                  int* __restrict__ offs,
                                                  int* __restrict__ cur) {
    __shared__ int sh[SCAN_B];
    int t = threadIdx.x;
    int i = blockIdx.x * SCAN_B + t;
    int v = (i < NN) ? deg[i] - 1 : 0;
    sh[t] = v;
    __syncthreads();
    for (int off = 1; off < SCAN_B; off <<= 1) {
        int u = (t >= off) ? sh[t - off] : 0;
        __syncthreads();
        sh[t] += u;
        __syncthreads();
    }
    if (i < NN) {
        int o = bpre[blockIdx.x] + sh[t] - v;
        offs[i] = o;
        cur[i] = o;
    }
    if (blockIdx.x == 0 && t == 0) offs[NN] = NE;
}

// XCD-localized chunked scatter (kills partial-line write amplification)
__global__ void k_scatter(const int* __restrict__ src, const int* __restrict__ dst,
                          int* __restrict__ cur, int* __restrict__ csrc) {
    int ch = blockIdx.x & (NCH - 1);
    int seg = blockIdx.x >> 3;
    int e = seg * 256 + threadIdx.x;
    if (e >= NE) return;
    int d = dst[e];
    int lo = ch * NPC;
    if (d < lo || d >= lo + NPC) return;
    int pos = atomicAdd(&cur[d], 1);
    csrc[pos] = src[e];
}

// u_out[n,:] = oscale[n] * (u_in[n,:] + sum_{s in Nin(n)} u_in[s,:])   fp16 rows
// hops 1,2: oscale = dn2 (1/deg); hop 3: oscale = dinv -> output is h = u3*sqrt(deg)
__global__ __launch_bounds__(256) void k_hop(const int* __restrict__ offs,
                                             const int* __restrict__ csrc,
                                             const float* __restrict__ oscale,
                                             const __half* __restrict__ uin,
                                             __half* __restrict__ uout) {
    int n = blockIdx.x * 4 + (threadIdx.x >> 6);
    if (n >= NN) return;
    int f = threadIdx.x & 63;
    float acc = __half2float(uin[n * F + f]);
    int e = offs[n], end = offs[n + 1];
    for (; e + 8 <= end; e += 8) {
        int s0 = csrc[e],     s1 = csrc[e + 1], s2 = csrc[e + 2], s3 = csrc[e + 3];
        int s4 = csrc[e + 4], s5 = csrc[e + 5], s6 = csrc[e + 6], s7 = csrc[e + 7];
        float h0 = __half2float(uin[s0 * F + f]);
        float h1 = __half2float(uin[s1 * F + f]);
        float h2 = __half2float(uin[s2 * F + f]);
        float h3 = __half2float(uin[s3 * F + f]);
        float h4 = __half2float(uin[s4 * F + f]);
        float h5 = __half2float(uin[s5 * F + f]);
        float h6 = __half2float(uin[s6 * F + f]);
        float h7 = __half2float(uin[s7 * F + f]);
        acc += ((h0 + h1) + (h2 + h3)) + ((h4 + h5) + (h6 + h7));
    }
    for (; e < end; ++e)
        acc += __half2float(uin[csrc[e] * F + f]);
    uout[n * F + f] = __float2half(oscale[n] * acc);
}

// y = relu(h @ Wh^T + b) via MFMA (fp16 in/out, fp32 accum); per-feature stats.
// Wave = 16-node tile. A: lane holds h[n0+(l&15)][32kk+8(l>>4)..+7].
// B: lane holds Wh[16ct+(l&15)][32kk+8(l>>4)..+7]. D: col=l&15, row=4(l>>4)+r.
__global__ __launch_bounds__(256) void k_linear(const __half* __restrict__ h,
                                                const __half* __restrict__ Wh,
                                                const float* __restrict__ bg,
                                                __half* __restrict__ y,
                                                float* __restrict__ sums) {
    __shared__ float sred[4][64], qred[4][64];
    int tid = threadIdx.x;
    int wid = tid >> 6, lane = tid & 63;
    int lo = lane & 15, hi = lane >> 4;
    int n0 = blockIdx.x * 64 + wid * 16;

    half8 bf[4][2];
#pragma unroll
    for (int ct = 0; ct < 4; ++ct)
#pragma unroll
        for (int kk = 0; kk < 2; ++kk)
            bf[ct][kk] = *(const half8*)(Wh + (ct * 16 + lo) * 64 + kk * 32 + hi * 8);

    int arow = n0 + lo;
    half8 af[2];
    if (arow < NN) {
        af[0] = *(const half8*)(h + arow * 64 + hi * 8);
        af[1] = *(const half8*)(h + arow * 64 + 32 + hi * 8);
    } else {
#pragma unroll
        for (int j = 0; j < 8; ++j) { af[0][j] = (_Float16)0; af[1][j] = (_Float16)0; }
    }

    f32x4 acc[4];
#pragma unroll
    for (int ct = 0; ct < 4; ++ct) {
        acc[ct] = (f32x4){0.f, 0.f, 0.f, 0.f};
        acc[ct] = __builtin_amdgcn_mfma_f32_16x16x32_f16(af[0], bf[ct][0], acc[ct], 0, 0, 0);
        acc[ct] = __builtin_amdgcn_mfma_f32_16x16x32_f16(af[1], bf[ct][1], acc[ct], 0, 0, 0);
    }

#pragma unroll
    for (int ct = 0; ct < 4; ++ct) {
        int j = ct * 16 + lo;
        float bj = bg[j];
        float ls = 0.f, lq = 0.f;
#pragma unroll
        for (int r = 0; r < 4; ++r) {
            int n = n0 + hi * 4 + r;
            if (n < NN) {
                float v = fmaxf(acc[ct][r] + bj, 0.f);
                y[n * 64 + j] = __float2half(v);
                ls += v; lq += v * v;
            }
        }
        ls += __shfl_xor(ls, 16, 64); ls += __shfl_xor(ls, 32, 64);
        lq += __shfl_xor(lq, 16, 64); lq += __shfl_xor(lq, 32, 64);
        if (hi == 0) { sred[wid][j] = ls; qred[wid][j] = lq; }
    }
    __syncthreads();
    if (tid < 64) {
        float S = sred[0][tid] + sred[1][tid] + sred[2][tid] + sred[3][tid];
        float Q = qred[0][tid] + qred[1][tid] + qred[2][tid] + qred[3][tid];
        fatomic_add(&sums[tid], S);
        fatomic_add(&sums[64 + tid], Q);
    }
}

__global__ void k_bnp(const float* __restrict__ sums, const float* __restrict__ gamma,
                      const float* __restrict__ beta, float* __restrict__ ac) {
    int j = threadIdx.x;   // 64
    float mean = sums[j] * (1.0f / NN);
    float var = sums[64 + j] * (1.0f / NN) - mean * mean;
    float rinv = rsqrtf(var + BN_EPS);
    float a = gamma[j] * rinv;
    ac[j] = a;
    ac[64 + j] = beta[j] - mean * a;
}

__global__ __launch_bounds__(256) void k_normpool(const __half* __restrict__ y,
                                                  const int* __restrict__ batch,
                                                  const float* __restrict__ ac,
                                                  float* __restrict__ outh,
                                                  float* __restrict__ pooled) {
    int tid = threadIdx.x;
    int j = tid & 63, nl = tid >> 6;
    float a = ac[j], c = ac[64 + j];
    int base = blockIdx.x * 256;
    int curg = -1;
    float acc = 0.f;
    for (int it = 0; it < 64; ++it) {
        int n = base + it * 4 + nl;
        if (n >= NN) break;
        int g = batch[n];
        float v = fmaf(__half2float(y[n * 64 + j]), a, c);
        outh[(size_t)n * 64 + j] = v;
        if (g != curg) {
            if (curg >= 0) fatomic_add(&pooled[curg * 64 + j], acc);
            curg = g; acc = 0.f;
        }
        acc += v;
    }
    if (curg >= 0) fatomic_add(&pooled[curg * 64 + j], acc);
}

extern "C" void kernel_launch(void* const* d_in, const int* in_sizes, int n_in,
                              void* d_out, int out_size, void* d_ws, size_t ws_size,
                              hipStream_t stream) {
    const float* x     = (const float*)d_in[0];
    const int*   ei    = (const int*)d_in[1];
    const int*   batch = (const int*)d_in[2];
    const float* W     = (const float*)d_in[3];
    const float* b     = (const float*)d_in[4];
    const float* gamma = (const float*)d_in[5];
    const float* beta  = (const float*)d_in[6];
    const int* src = ei;
    const int* dst = ei + NE;

    float* pooled = (float*)d_out;
    float* outh   = (float*)d_out + NG * F;

    char* w = (char*)d_ws;
    float* dinv = (float*)w;  w += sizeof(float) * NN;
    float* dn2  = (float*)w;  w += sizeof(float) * NN;
    int*   offs = (int*)w;    w += sizeof(int) * (NN + 1);
    float* sums = (float*)w;  w += sizeof(float) * 2 * F;
    float* ac   = (float*)w;  w += sizeof(float) * 2 * F;
    int*   bsum = (int*)w;    w += sizeof(int) * 128;
    int*   bpre = (int*)w;    w += sizeof(int) * 128;
    __half* Wh  = (__half*)w; w += sizeof(__half) * F * F;
    int*   csrc = (int*)w;    w += sizeof(int) * NE;
    // union: deg+cur (0.8 MB, CSR build only) | ubufA+ubufB (25.6 MB, hops on)
    char* uni = w;
    int*    deg   = (int*)uni;
    int*    cur   = (int*)(uni + sizeof(int) * NN);
    __half* ubufA = (__half*)uni;
    __half* ubufB = (__half*)(uni + sizeof(__half) * NN * F);

    const int B = 256;
    dim3 blk(B);

    k_init<<<dim3((NN + B - 1) / B), blk, 0, stream>>>(deg, pooled, sums);
    k_deg<<<dim3((NE + B - 1) / B), blk, 0, stream>>>(dst, deg);
    k_prec<<<dim3((NN + B - 1) / B), blk, 0, stream>>>(deg, dinv, dn2);
    k_wh<<<dim3(16), blk, 0, stream>>>(W, Wh);
    k_scan1<<<dim3(NBLK), dim3(SCAN_B), 0, stream>>>(deg, bsum);
    k_scan2<<<dim3(1), dim3(128), 0, stream>>>(bsum, bpre);
    k_scan3<<<dim3(NBLK), dim3(SCAN_B), 0, stream>>>(deg, bpre, offs, cur);
    k_scatter<<<dim3(((NE + B - 1) / B) * NCH), blk, 0, stream>>>(src, dst, cur, csrc);

    // u0 = dinv.x -> ubufA  (deg/cur dead from here on)
    k_u0<<<dim3((NN * F / 2 + B - 1) / B), blk, 0, stream>>>((const float2*)x, dinv, (__half2*)ubufA);

    dim3 gh((NN + 3) / 4);   // 25000 blocks, 1 wave per node
    k_hop<<<gh, blk, 0, stream>>>(offs, csrc, dn2,  ubufA, ubufB);   // hop 1
    k_hop<<<gh, blk, 0, stream>>>(offs, csrc, dn2,  ubufB, ubufA);   // hop 2
    k_hop<<<gh, blk, 0, stream>>>(offs, csrc, dinv, ubufA, ubufB);   // hop 3 -> h

    // linear + relu + BN stats (MFMA): ubufB(h) -> y in ubufA
    __half* yh = ubufA;
    k_linear<<<dim3((NN + 63) / 64), blk, 0, stream>>>(ubufB, Wh, b, yh, sums);
    k_bnp<<<dim3(1), dim3(64), 0, stream>>>(sums, gamma, beta, ac);
    k_normpool<<<dim3((NN + 255) / 256), blk, 0, stream>>>(yh, batch, ac, outh, pooled);
}

// Round 7
// 404.240 us; speedup vs baseline: 3.1032x; 1.1377x over previous
//
#include <hip/hip_runtime.h>
#include <hip/hip_fp16.h>

#define NN 100000
#define NE 1600000
#define F 64
#define NG 64
#define BN_EPS 1e-5f
#define SCAN_B 1024
#define NBLK ((NN + SCAN_B - 1) / SCAN_B)   // 98
#define NCH 8
#define NPC (NN / NCH)                       // 12500 nodes per chunk

typedef _Float16 half8 __attribute__((ext_vector_type(8)));
typedef float f32x4 __attribute__((ext_vector_type(4)));

__device__ __forceinline__ float fatomic_add(float* p, float v) {
    return unsafeAtomicAdd(p, v);   // native global_atomic_add_f32
}

// deg=1 (self loop), pooled=0, sums=0, Wh = fp16(W)
__global__ void k_init(int* __restrict__ deg, float* __restrict__ pooled,
                       float* __restrict__ sums, const float* __restrict__ Wg,
                       __half* __restrict__ Wh) {
    int i = blockIdx.x * blockDim.x + threadIdx.x;
    if (i < NN) deg[i] = 1;
    if (i < NG * F) pooled[i] = 0.f;
    if (i < 2 * F) sums[i] = 0.f;
    if (i < F * F) Wh[i] = __float2half(Wg[i]);
}

// XCD-localized chunked degree count (atomics stay in one XCD's L2)
__global__ void k_deg(const int* __restrict__ dst, int* __restrict__ deg) {
    int ch = blockIdx.x & (NCH - 1);
    int e = (blockIdx.x >> 3) * 256 + threadIdx.x;
    if (e >= NE) return;
    int d = dst[e];
    int lo = ch * NPC;
    if (d < lo || d >= lo + NPC) return;
    atomicAdd(&deg[d], 1);
}

// pass 1: per-block sum of (deg-1); also dinv = deg^-1/2, dn2 = 1/deg
__global__ __launch_bounds__(SCAN_B) void k_scan1(const int* __restrict__ deg,
                                                  int* __restrict__ bsum,
                                                  float* __restrict__ dinv,
                                                  float* __restrict__ dn2) {
    int t = threadIdx.x;
    int i = blockIdx.x * SCAN_B + t;
    int d = (i < NN) ? deg[i] : 1;
    if (i < NN) {
        float df = (float)d;
        float r = rsqrtf(df);
        dinv[i] = r;
        dn2[i] = r * r;
    }
    int v = d - 1;
#pragma unroll
    for (int o = 32; o > 0; o >>= 1) v += __shfl_down(v, o, 64);
    __shared__ int ws[16];
    if ((t & 63) == 0) ws[t >> 6] = v;
    __syncthreads();
    if (t == 0) {
        int s = 0;
#pragma unroll
        for (int k = 0; k < 16; ++k) s += ws[k];
        bsum[blockIdx.x] = s;
    }
}

// pass 2 (inlined scan of block sums) + pass 3: global exclusive offs, cur
__global__ __launch_bounds__(SCAN_B) void k_scan3(const int* __restrict__ deg,
                                                  const int* __restrict__ bsum,
                                                  int* __restrict__ offs,
                                                  int* __restrict__ cur) {
    __shared__ int sh[SCAN_B];
    __shared__ int bsh[128];
    int t = threadIdx.x;
    if (t < 128) bsh[t] = (t < NBLK) ? bsum[t] : 0;
    __syncthreads();
    for (int off = 1; off < 128; off <<= 1) {
        int u = (t < 128 && t >= off) ? bsh[t - off] : 0;
        __syncthreads();
        if (t < 128) bsh[t] += u;
        __syncthreads();
    }
    int bpre = (blockIdx.x > 0) ? bsh[blockIdx.x - 1] : 0;   // exclusive blk prefix
    int i = blockIdx.x * SCAN_B + t;
    int v = (i < NN) ? deg[i] - 1 : 0;
    sh[t] = v;
    __syncthreads();
    for (int off = 1; off < SCAN_B; off <<= 1) {
        int u = (t >= off) ? sh[t - off] : 0;
        __syncthreads();
        sh[t] += u;
        __syncthreads();
    }
    if (i < NN) {
        int o = bpre + sh[t] - v;
        offs[i] = o;
        cur[i] = o;
    }
    if (blockIdx.x == 0 && t == 0) offs[NN] = NE;
}

// XCD-localized chunked scatter (kills partial-line write amplification)
__global__ void k_scatter(const int* __restrict__ src, const int* __restrict__ dst,
                          int* __restrict__ cur, int* __restrict__ csrc) {
    int ch = blockIdx.x & (NCH - 1);
    int e = (blockIdx.x >> 3) * 256 + threadIdx.x;
    if (e >= NE) return;
    int d = dst[e];
    int lo = ch * NPC;
    if (d < lo || d >= lo + NPC) return;
    int pos = atomicAdd(&cur[d], 1);
    csrc[pos] = src[e];
}

// u0 = dinv (.) x   (fp32 -> fp16, 2 elems/thread)
__global__ void k_u0(const float2* __restrict__ x2, const float* __restrict__ dinv,
                     __half2* __restrict__ u2) {
    int i = blockIdx.x * blockDim.x + threadIdx.x;   // NN*F/2
    if (i >= NN * F / 2) return;
    float2 v = x2[i];
    float d = dinv[i >> 5];                           // node = (2i)>>6
    u2[i] = __floats2half2_rn(v.x * d, v.y * d);
}

// u_out[n,:] = oscale[n] * (u_in[n,:] + sum_{s in Nin(n)} u_in[s,:])
// wave = 2 nodes: lanes 0-31 -> node 2w, lanes 32-63 -> node 2w+1; lane = __half2 col
__global__ __launch_bounds__(256) void k_hop(const int* __restrict__ offs,
                                             const int* __restrict__ csrc,
                                             const float* __restrict__ oscale,
                                             const __half2* __restrict__ uin,
                                             __half2* __restrict__ uout) {
    int wv = blockIdx.x * 4 + (threadIdx.x >> 6);
    int lane = threadIdx.x & 63;
    int n = wv * 2 + (lane >> 5);      // NN = 12500*4*2 exactly
    int c = lane & 31;
    float2 acc = __half22float2(uin[n * 32 + c]);
    int e = offs[n], end = offs[n + 1];
    for (; e + 8 <= end; e += 8) {
        int s0 = csrc[e],     s1 = csrc[e + 1], s2 = csrc[e + 2], s3 = csrc[e + 3];
        int s4 = csrc[e + 4], s5 = csrc[e + 5], s6 = csrc[e + 6], s7 = csrc[e + 7];
        float2 f0 = __half22float2(uin[s0 * 32 + c]);
        float2 f1 = __half22float2(uin[s1 * 32 + c]);
        float2 f2 = __half22float2(uin[s2 * 32 + c]);
        float2 f3 = __half22float2(uin[s3 * 32 + c]);
        float2 f4 = __half22float2(uin[s4 * 32 + c]);
        float2 f5 = __half22float2(uin[s5 * 32 + c]);
        float2 f6 = __half22float2(uin[s6 * 32 + c]);
        float2 f7 = __half22float2(uin[s7 * 32 + c]);
        acc.x += ((f0.x + f1.x) + (f2.x + f3.x)) + ((f4.x + f5.x) + (f6.x + f7.x));
        acc.y += ((f0.y + f1.y) + (f2.y + f3.y)) + ((f4.y + f5.y) + (f6.y + f7.y));
    }
    for (; e < end; ++e) {
        float2 f = __half22float2(uin[csrc[e] * 32 + c]);
        acc.x += f.x; acc.y += f.y;
    }
    float os = oscale[n];
    uout[n * 32 + c] = __floats2half2_rn(acc.x * os, acc.y * os);
}

// y = relu(h @ Wh^T + b) via MFMA (fp16 in/out, fp32 accum); per-feature stats.
__global__ __launch_bounds__(256) void k_linear(const __half* __restrict__ h,
                                                const __half* __restrict__ Wh,
                                                const float* __restrict__ bg,
                                                __half* __restrict__ y,
                                                float* __restrict__ sums) {
    __shared__ float sred[4][64], qred[4][64];
    int tid = threadIdx.x;
    int wid = tid >> 6, lane = tid & 63;
    int lo = lane & 15, hi = lane >> 4;
    int n0 = blockIdx.x * 64 + wid * 16;

    half8 bf[4][2];
#pragma unroll
    for (int ct = 0; ct < 4; ++ct)
#pragma unroll
        for (int kk = 0; kk < 2; ++kk)
            bf[ct][kk] = *(const half8*)(Wh + (ct * 16 + lo) * 64 + kk * 32 + hi * 8);

    int arow = n0 + lo;
    half8 af[2];
    if (arow < NN) {
        af[0] = *(const half8*)(h + arow * 64 + hi * 8);
        af[1] = *(const half8*)(h + arow * 64 + 32 + hi * 8);
    } else {
#pragma unroll
        for (int j = 0; j < 8; ++j) { af[0][j] = (_Float16)0; af[1][j] = (_Float16)0; }
    }

    f32x4 acc[4];
#pragma unroll
    for (int ct = 0; ct < 4; ++ct) {
        acc[ct] = (f32x4){0.f, 0.f, 0.f, 0.f};
        acc[ct] = __builtin_amdgcn_mfma_f32_16x16x32_f16(af[0], bf[ct][0], acc[ct], 0, 0, 0);
        acc[ct] = __builtin_amdgcn_mfma_f32_16x16x32_f16(af[1], bf[ct][1], acc[ct], 0, 0, 0);
    }

#pragma unroll
    for (int ct = 0; ct < 4; ++ct) {
        int j = ct * 16 + lo;
        float bj = bg[j];
        float ls = 0.f, lq = 0.f;
#pragma unroll
        for (int r = 0; r < 4; ++r) {
            int n = n0 + hi * 4 + r;
            if (n < NN) {
                float v = fmaxf(acc[ct][r] + bj, 0.f);
                y[n * 64 + j] = __float2half(v);
                ls += v; lq += v * v;
            }
        }
        ls += __shfl_xor(ls, 16, 64); ls += __shfl_xor(ls, 32, 64);
        lq += __shfl_xor(lq, 16, 64); lq += __shfl_xor(lq, 32, 64);
        if (hi == 0) { sred[wid][j] = ls; qred[wid][j] = lq; }
    }
    __syncthreads();
    if (tid < 64) {
        float S = sred[0][tid] + sred[1][tid] + sred[2][tid] + sred[3][tid];
        float Q = qred[0][tid] + qred[1][tid] + qred[2][tid] + qred[3][tid];
        fatomic_add(&sums[tid], S);
        fatomic_add(&sums[64 + tid], Q);
    }
}

// BN affine (recomputed per block from sums) + normalize + pooled segment-sum
__global__ __launch_bounds__(256) void k_normpool(const __half* __restrict__ y,
                                                  const int* __restrict__ batch,
                                                  const float* __restrict__ sums,
                                                  const float* __restrict__ gamma,
                                                  const float* __restrict__ beta,
                                                  float* __restrict__ outh,
                                                  float* __restrict__ pooled) {
    int tid = threadIdx.x;
    int j = tid & 63, nl = tid >> 6;
    float mean = sums[j] * (1.0f / NN);
    float var = sums[64 + j] * (1.0f / NN) - mean * mean;
    float rinv = rsqrtf(var + BN_EPS);
    float a = gamma[j] * rinv;
    float c = beta[j] - mean * a;
    int base = blockIdx.x * 256;
    int curg = -1;
    float acc = 0.f;
    for (int it = 0; it < 64; ++it) {
        int n = base + it * 4 + nl;
        if (n >= NN) break;
        int g = batch[n];
        float v = fmaf(__half2float(y[n * 64 + j]), a, c);
        outh[(size_t)n * 64 + j] = v;
        if (g != curg) {
            if (curg >= 0) fatomic_add(&pooled[curg * 64 + j], acc);
            curg = g; acc = 0.f;
        }
        acc += v;
    }
    if (curg >= 0) fatomic_add(&pooled[curg * 64 + j], acc);
}

extern "C" void kernel_launch(void* const* d_in, const int* in_sizes, int n_in,
                              void* d_out, int out_size, void* d_ws, size_t ws_size,
                              hipStream_t stream) {
    const float* x     = (const float*)d_in[0];
    const int*   ei    = (const int*)d_in[1];
    const int*   batch = (const int*)d_in[2];
    const float* W     = (const float*)d_in[3];
    const float* b     = (const float*)d_in[4];
    const float* gamma = (const float*)d_in[5];
    const float* beta  = (const float*)d_in[6];
    const int* src = ei;
    const int* dst = ei + NE;

    float* pooled = (float*)d_out;
    float* outh   = (float*)d_out + NG * F;

    char* w = (char*)d_ws;
    float* dinv = (float*)w;  w += sizeof(float) * NN;
    float* dn2  = (float*)w;  w += sizeof(float) * NN;
    int*   offs = (int*)w;    w += sizeof(int) * (NN + 1);
    float* sums = (float*)w;  w += sizeof(float) * 2 * F;
    int*   bsum = (int*)w;    w += sizeof(int) * 128;
    __half* Wh  = (__half*)w; w += sizeof(__half) * F * F;
    int*   csrc = (int*)w;    w += sizeof(int) * NE;
    // union: deg+cur (0.8 MB, CSR build only) | ubufA+ubufB (25.6 MB, hops on)
    char* uni = w;
    int*    deg   = (int*)uni;
    int*    cur   = (int*)(uni + sizeof(int) * NN);
    __half* ubufA = (__half*)uni;
    __half* ubufB = (__half*)(uni + sizeof(__half) * NN * F);

    const int B = 256;
    dim3 blk(B);
    dim3 gch(((NE + B - 1) / B) * NCH);

    k_init<<<dim3((NN + B - 1) / B), blk, 0, stream>>>(deg, pooled, sums, W, Wh);
    k_deg<<<gch, blk, 0, stream>>>(dst, deg);
    k_scan1<<<dim3(NBLK), dim3(SCAN_B), 0, stream>>>(deg, bsum, dinv, dn2);
    k_scan3<<<dim3(NBLK), dim3(SCAN_B), 0, stream>>>(deg, bsum, offs, cur);
    k_scatter<<<gch, blk, 0, stream>>>(src, dst, cur, csrc);

    // u0 = dinv.x -> ubufA  (deg/cur dead from here on)
    k_u0<<<dim3((NN * F / 2 + B - 1) / B), blk, 0, stream>>>((const float2*)x, dinv, (__half2*)ubufA);

    dim3 gh(NN / 8);   // 12500 blocks, 4 waves/block, 2 nodes/wave
    k_hop<<<gh, blk, 0, stream>>>(offs, csrc, dn2,  (const __half2*)ubufA, (__half2*)ubufB);
    k_hop<<<gh, blk, 0, stream>>>(offs, csrc, dn2,  (const __half2*)ubufB, (__half2*)ubufA);
    k_hop<<<gh, blk, 0, stream>>>(offs, csrc, dinv, (const __half2*)ubufA, (__half2*)ubufB);

    // linear + relu + BN stats (MFMA): ubufB(h) -> y in ubufA
    __half* yh = ubufA;
    k_linear<<<dim3((NN + 63) / 64), blk, 0, stream>>>(ubufB, Wh, b, yh, sums);
    k_normpool<<<dim3((NN + 255) / 256), blk, 0, stream>>>(yh, batch, sums, gamma, beta, outh, pooled);
}